// Round 12
// baseline (364.993 us; speedup 1.0000x reference)
//
#include <hip/hip_runtime.h>

#define DD 300
#define KK 50
#define BB 32
#define SS 8192
#define NN 128
#define LL 64
#define NSEG (BB * NN)   // 4096
#define TMU 8            // segments per k_u block
#define NTU 320
#define TTP 304          // Tt row pitch (floats)
#define TTR 64           // Tt padded rows

__device__ __forceinline__ float wave_sum(float v) {
    #pragma unroll
    for (int m = 32; m; m >>= 1) v += __shfl_xor(v, m, 64);
    return v;
}
__device__ __forceinline__ float wave_max(float v) {
    #pragma unroll
    for (int m = 32; m; m >>= 1) v = fmaxf(v, __shfl_xor(v, m, 64));
    return v;
}
__device__ __forceinline__ float dot4(float4 a, float4 b) {
    return a.x * b.x + a.y * b.y + a.z * b.z + a.w * b.w;
}
__device__ __forceinline__ void fma4(float4& acc, float s, float4 v) {
    acc.x += s * v.x; acc.y += s * v.y; acc.z += s * v.z; acc.w += s * v.w;
}
__device__ __forceinline__ void scale4(float4& a, float s) {
    a.x *= s; a.y *= s; a.z *= s; a.w *= s;
}

// 4 emb rows (token via shfl, row clamped to len-1); A = dims 4*lane.., B = 44+4*lane (lanes>=53)
__device__ __forceinline__ void ld_rows(const float* __restrict__ emb, int tok, int len,
                                        int l0, int lane, bool bl, float4* A, float4* B) {
    #pragma unroll
    for (int i = 0; i < 4; ++i) {
        int lc = l0 + i; lc = (lc < len) ? lc : (len - 1);
        const int t = __shfl(tok, lc);
        const float4* r4 = (const float4*)(emb + (size_t)t * DD);
        A[i] = r4[lane];
        if (bl) B[i] = r4[11 + lane];
    }
}
__device__ __forceinline__ void ld_wrows(const float* __restrict__ W, int rmax, int pitch,
                                         int k0, int lane, bool bl, float4* A, float4* B) {
    #pragma unroll
    for (int i = 0; i < 4; ++i) {
        int kc = k0 + i; kc = (kc < rmax) ? kc : rmax;
        const float4* r4 = (const float4*)(W + (size_t)kc * pitch);
        A[i] = r4[lane];
        if (bl) B[i] = r4[11 + lane];
    }
}

// ============ K0: transpose T_w [300][50] -> Tt [64][304] (zero padded) ============
__global__ __launch_bounds__(TTP) void k_tt(const float* __restrict__ T_w,
                                            float* __restrict__ Tt) {
    const int k = blockIdx.x;
    const int d = threadIdx.x;
    float v = 0.f;
    if (k < KK && d < DD) v = T_w[(size_t)d * KK + k];
    Tt[(size_t)k * TTP + d] = v;
}

// ============ K1: y — wave-per-segment chunk-8 gather (bounded) ============
__global__ __launch_bounds__(256, 4) void k_y1(
    const float* __restrict__ emb,
    const int*   __restrict__ tokens,
    const int*   __restrict__ seg_starts,
    const int*   __restrict__ seg_lens,
    float* __restrict__ out_y)
{
    const int lane = threadIdx.x & 63;
    const int seg  = blockIdx.x * 4 + (threadIdx.x >> 6);
    const int len  = seg_lens[seg];
    const int base = (seg >> 7) * SS + seg_starts[seg];
    const int tok  = tokens[base + lane];
    const bool bl  = (lane >= 53);

    float4 A0[4], B0[4], A1[4], B1[4];
    #pragma unroll
    for (int i = 0; i < 4; ++i) {
        B0[i] = make_float4(0.f, 0.f, 0.f, 0.f);
        B1[i] = make_float4(0.f, 0.f, 0.f, 0.f);
    }
    float4 aA = make_float4(0.f, 0.f, 0.f, 0.f);
    float4 aB = make_float4(0.f, 0.f, 0.f, 0.f);

    const int len8 = (len + 7) & ~7;
    ld_rows(emb, tok, len, 0, lane, bl, A0, B0);
    for (int l0 = 0; l0 < len8; l0 += 8) {
        ld_rows(emb, tok, len, l0 + 4, lane, bl, A1, B1);
        #pragma unroll
        for (int i = 0; i < 4; ++i) {
            const float m = (l0 + i < len) ? 1.f : 0.f;
            fma4(aA, m, A0[i]); fma4(aB, m, B0[i]);
        }
        ld_rows(emb, tok, len, l0 + 8, lane, bl, A0, B0);
        #pragma unroll
        for (int i = 0; i < 4; ++i) {
            const float m = (l0 + 4 + i < len) ? 1.f : 0.f;
            fma4(aA, m, A1[i]); fma4(aB, m, B1[i]);
        }
    }
    const float inv = 1.f / (float)len;
    scale4(aA, inv); scale4(aB, inv);
    float4* yo = (float4*)(out_y + (size_t)seg * DD);
    yo[lane] = aA;
    if (bl) yo[11 + lane] = aB;
}

// ============ K2: u = y @ M_w ============
__global__ __launch_bounds__(NTU) void k_u(
    const float* __restrict__ y,
    const float* __restrict__ M_w,
    float* __restrict__ u)
{
    const int tid  = threadIdx.x;
    const int row0 = blockIdx.x * TMU;
    if (tid >= DD) return;

    float acc[TMU];
    #pragma unroll
    for (int r = 0; r < TMU; ++r) acc[r] = 0.f;

    #pragma unroll 5
    for (int e = 0; e < DD; ++e) {
        const float m = M_w[(size_t)e * DD + tid];
        #pragma unroll
        for (int r = 0; r < TMU; ++r)
            acc[r] += m * y[(size_t)(row0 + r) * DD + e];
    }
    #pragma unroll
    for (int r = 0; r < TMU; ++r)
        u[(size_t)(row0 + r) * DD + tid] = acc[r];
}

// ============ K3: ONLINE-softmax fused esc+z (single gather pass), then p, r ============
__global__ __launch_bounds__(256, 4) void k_rest(
    const float* __restrict__ emb,
    const float* __restrict__ W_w,    // [K, D]
    const float* __restrict__ T_w,    // [D, K] (fallback)
    const float* __restrict__ Tt,     // [TTR, TTP]
    const int    use_tt,
    const int*   __restrict__ tokens,
    const int*   __restrict__ seg_starts,
    const int*   __restrict__ seg_lens,
    const float* __restrict__ u_ws,
    float* __restrict__ out_z,
    float* __restrict__ out_p,
    float* __restrict__ out_r)
{
    const int lane = threadIdx.x & 63;
    const int seg  = blockIdx.x * 4 + (threadIdx.x >> 6);
    const int len  = seg_lens[seg];
    const int base = (seg >> 7) * SS + seg_starts[seg];
    const int tok  = tokens[base + lane];
    const bool bl  = (lane >= 53);

    const float4* u4 = (const float4*)(u_ws + (size_t)seg * DD);
    const float4 U0 = u4[lane];
    float4 U1 = make_float4(0.f, 0.f, 0.f, 0.f);
    if (bl) U1 = u4[11 + lane];

    float4 A0[4], B0[4], A1[4], B1[4];
    #pragma unroll
    for (int i = 0; i < 4; ++i) {
        B0[i] = make_float4(0.f, 0.f, 0.f, 0.f);
        B1[i] = make_float4(0.f, 0.f, 0.f, 0.f);
    }

    // ---- single pass: online softmax-weighted accumulation ----
    float m = -INFINITY, s = 0.f;
    float4 zA = make_float4(0.f, 0.f, 0.f, 0.f);
    float4 zB = make_float4(0.f, 0.f, 0.f, 0.f);

#define PROC4(A, B, BASE)                                                        \
    {                                                                            \
        float d0 = wave_sum(dot4(A[0], U0) + dot4(B[0], U1));                    \
        float d1 = wave_sum(dot4(A[1], U0) + dot4(B[1], U1));                    \
        float d2 = wave_sum(dot4(A[2], U0) + dot4(B[2], U1));                    \
        float d3 = wave_sum(dot4(A[3], U0) + dot4(B[3], U1));                    \
        const float e0 = ((BASE) + 0 < len) ? d0 : -INFINITY;                    \
        const float e1 = ((BASE) + 1 < len) ? d1 : -INFINITY;                    \
        const float e2 = ((BASE) + 2 < len) ? d2 : -INFINITY;                    \
        const float e3 = ((BASE) + 3 < len) ? d3 : -INFINITY;                    \
        const float g = fmaxf(fmaxf(e0, e1), fmaxf(e2, e3));                     \
        if (g > m) {                                                             \
            const float sc = __expf(m - g);   /* exp(-inf)=0 on first group */   \
            s *= sc; scale4(zA, sc); scale4(zB, sc); m = g;                      \
        }                                                                        \
        const float w0 = ((BASE) + 0 < len) ? __expf(d0 - m) : 0.f;              \
        const float w1 = ((BASE) + 1 < len) ? __expf(d1 - m) : 0.f;              \
        const float w2 = ((BASE) + 2 < len) ? __expf(d2 - m) : 0.f;              \
        const float w3 = ((BASE) + 3 < len) ? __expf(d3 - m) : 0.f;              \
        s += w0 + w1 + w2 + w3;                                                  \
        fma4(zA, w0, A[0]); fma4(zB, w0, B[0]);                                  \
        fma4(zA, w1, A[1]); fma4(zB, w1, B[1]);                                  \
        fma4(zA, w2, A[2]); fma4(zB, w2, B[2]);                                  \
        fma4(zA, w3, A[3]); fma4(zB, w3, B[3]);                                  \
    }

    const int len8 = (len + 7) & ~7;
    ld_rows(emb, tok, len, 0, lane, bl, A0, B0);
    for (int l0 = 0; l0 < len8; l0 += 8) {
        ld_rows(emb, tok, len, l0 + 4, lane, bl, A1, B1);
        PROC4(A0, B0, l0)
        ld_rows(emb, tok, len, l0 + 8, lane, bl, A0, B0);
        PROC4(A1, B1, l0 + 4)
    }
#undef PROC4

    const float invs = 1.f / s;
    scale4(zA, invs); scale4(zB, invs);
    {
        float4* zo = (float4*)(out_z + (size_t)seg * DD);
        zo[lane] = zA;
        if (bl) zo[11 + lane] = zB;
    }

    // ---- p: 50 wave-dots vs register z, chunk-8 (rows clamped to 49) ----
    float sc = 0.f;
    ld_wrows(W_w, KK - 1, DD, 0, lane, bl, A0, B0);
    for (int k0 = 0; k0 < 56; k0 += 8) {
        ld_wrows(W_w, KK - 1, DD, k0 + 4, lane, bl, A1, B1);
        {
            float t0 = wave_sum(dot4(A0[0], zA) + dot4(B0[0], zB));
            float t1 = wave_sum(dot4(A0[1], zA) + dot4(B0[1], zB));
            float t2 = wave_sum(dot4(A0[2], zA) + dot4(B0[2], zB));
            float t3 = wave_sum(dot4(A0[3], zA) + dot4(B0[3], zB));
            sc = (lane == k0 + 0) ? t0 : sc;
            sc = (lane == k0 + 1) ? t1 : sc;
            sc = (lane == k0 + 2) ? t2 : sc;
            sc = (lane == k0 + 3) ? t3 : sc;
        }
        ld_wrows(W_w, KK - 1, DD, k0 + 8, lane, bl, A0, B0);
        {
            float t0 = wave_sum(dot4(A1[0], zA) + dot4(B1[0], zB));
            float t1 = wave_sum(dot4(A1[1], zA) + dot4(B1[1], zB));
            float t2 = wave_sum(dot4(A1[2], zA) + dot4(B1[2], zB));
            float t3 = wave_sum(dot4(A1[3], zA) + dot4(B1[3], zB));
            sc = (lane == k0 + 4) ? t0 : sc;
            sc = (lane == k0 + 5) ? t1 : sc;
            sc = (lane == k0 + 6) ? t2 : sc;
            sc = (lane == k0 + 7) ? t3 : sc;
        }
    }
    const float vk  = (lane < KK) ? sc : -INFINITY;
    const float mxk = wave_max(vk);
    const float ek  = (lane < KK) ? __expf(vk - mxk) : 0.f;
    const float smk = wave_sum(ek);
    const float p   = ek / smk;
    if (lane < KK) out_p[(size_t)seg * KK + lane] = p;

    // ---- r = p @ T_w.T ----
    float4 rA = make_float4(0.f, 0.f, 0.f, 0.f);
    float4 rB = make_float4(0.f, 0.f, 0.f, 0.f);
    if (use_tt) {
        ld_wrows(Tt, TTR - 1, TTP, 0, lane, bl, A0, B0);
        for (int k0 = 0; k0 < 56; k0 += 8) {
            ld_wrows(Tt, TTR - 1, TTP, k0 + 4, lane, bl, A1, B1);
            #pragma unroll
            for (int i = 0; i < 4; ++i) {
                const float pk = __shfl(p, k0 + i);
                fma4(rA, pk, A0[i]); fma4(rB, pk, B0[i]);
            }
            ld_wrows(Tt, TTR - 1, TTP, k0 + 8, lane, bl, A0, B0);
            #pragma unroll
            for (int i = 0; i < 4; ++i) {
                const float pk = __shfl(p, k0 + 4 + i);
                fma4(rA, pk, A1[i]); fma4(rB, pk, B1[i]);
            }
        }
    } else {
        const int dA = 4 * lane, dB = 44 + 4 * lane;
        for (int k = 0; k < KK; ++k) {
            const float pk = __shfl(p, k);
            rA.x += pk * T_w[(size_t)(dA + 0) * KK + k];
            rA.y += pk * T_w[(size_t)(dA + 1) * KK + k];
            rA.z += pk * T_w[(size_t)(dA + 2) * KK + k];
            rA.w += pk * T_w[(size_t)(dA + 3) * KK + k];
            if (bl) {
                rB.x += pk * T_w[(size_t)(dB + 0) * KK + k];
                rB.y += pk * T_w[(size_t)(dB + 1) * KK + k];
                rB.z += pk * T_w[(size_t)(dB + 2) * KK + k];
                rB.w += pk * T_w[(size_t)(dB + 3) * KK + k];
            }
        }
    }
    {
        float4* ro = (float4*)(out_r + (size_t)seg * DD);
        ro[lane] = rA;
        if (bl) ro[11 + lane] = rB;
    }
}

extern "C" void kernel_launch(void* const* d_in, const int* in_sizes, int n_in,
                              void* d_out, int out_size, void* d_ws, size_t ws_size,
                              hipStream_t stream) {
    const float* emb        = (const float*)d_in[0];
    const float* M_w        = (const float*)d_in[1];
    const float* W_w        = (const float*)d_in[2];
    const float* T_w        = (const float*)d_in[3];
    const int*   tokens     = (const int*)d_in[4];
    const int*   seg_starts = (const int*)d_in[5];
    const int*   seg_lens   = (const int*)d_in[6];

    float* out   = (float*)d_out;
    float* out_y = out;
    float* out_z = out + (size_t)NSEG * DD;
    float* out_p = out + (size_t)2 * NSEG * DD;
    float* out_r = out + (size_t)2 * NSEG * DD + (size_t)NSEG * KK;

    float* u_ws = (float*)d_ws;                              // NSEG*DD floats
    float* Tt   = u_ws + (size_t)NSEG * DD;                  // TTR*TTP floats
    const size_t need = ((size_t)NSEG * DD + (size_t)TTR * TTP) * sizeof(float);
    const int use_tt = (ws_size >= need) ? 1 : 0;

    if (use_tt)
        hipLaunchKernelGGL(k_tt, dim3(TTR), dim3(TTP), 0, stream, T_w, Tt);
    hipLaunchKernelGGL(k_y1, dim3(NSEG / 4), dim3(256), 0, stream,
                       emb, tokens, seg_starts, seg_lens, out_y);
    hipLaunchKernelGGL(k_u, dim3(NSEG / TMU), dim3(NTU), 0, stream,
                       out_y, M_w, u_ws);
    hipLaunchKernelGGL(k_rest, dim3(NSEG / 4), dim3(256), 0, stream,
                       emb, W_w, T_w, Tt, use_tt, tokens, seg_starts, seg_lens,
                       u_ws, out_z, out_p, out_r);
}

// Round 13
// 325.097 us; speedup vs baseline: 1.1227x; 1.1227x over previous
//
#include <hip/hip_runtime.h>

#define DD 300
#define KK 50
#define BB 32
#define SS 8192
#define NN 128
#define LL 64
#define NSEG (BB * NN)   // 4096
#define TMU 8            // segments per k_u block
#define NTU 320
#define TTP 304          // Tt row pitch (floats)
#define TTR 64           // Tt padded rows

__device__ __forceinline__ float wave_sum(float v) {
    #pragma unroll
    for (int m = 32; m; m >>= 1) v += __shfl_xor(v, m, 64);
    return v;
}
__device__ __forceinline__ float wave_max(float v) {
    #pragma unroll
    for (int m = 32; m; m >>= 1) v = fmaxf(v, __shfl_xor(v, m, 64));
    return v;
}
__device__ __forceinline__ float dot4(float4 a, float4 b) {
    return a.x * b.x + a.y * b.y + a.z * b.z + a.w * b.w;
}
__device__ __forceinline__ void fma4(float4& acc, float s, float4 v) {
    acc.x += s * v.x; acc.y += s * v.y; acc.z += s * v.z; acc.w += s * v.w;
}
__device__ __forceinline__ void scale4(float4& a, float s) {
    a.x *= s; a.y *= s; a.z *= s; a.w *= s;
}

// 4 emb rows (token via shfl, row clamped to len-1); A = dims 4*lane.., B = 44+4*lane (lanes>=53)
__device__ __forceinline__ void ld_rows(const float* __restrict__ emb, int tok, int len,
                                        int l0, int lane, bool bl, float4* A, float4* B) {
    #pragma unroll
    for (int i = 0; i < 4; ++i) {
        int lc = l0 + i; lc = (lc < len) ? lc : (len - 1);
        const int t = __shfl(tok, lc);
        const float4* r4 = (const float4*)(emb + (size_t)t * DD);
        A[i] = r4[lane];
        if (bl) B[i] = r4[11 + lane];
    }
}
__device__ __forceinline__ void ld_wrows(const float* __restrict__ W, int rmax, int pitch,
                                         int k0, int lane, bool bl, float4* A, float4* B) {
    #pragma unroll
    for (int i = 0; i < 4; ++i) {
        int kc = k0 + i; kc = (kc < rmax) ? kc : rmax;
        const float4* r4 = (const float4*)(W + (size_t)kc * pitch);
        A[i] = r4[lane];
        if (bl) B[i] = r4[11 + lane];
    }
}

// ============ K0: transpose T_w [300][50] -> Tt [64][304] (zero padded) ============
__global__ __launch_bounds__(TTP) void k_tt(const float* __restrict__ T_w,
                                            float* __restrict__ Tt) {
    const int k = blockIdx.x;
    const int d = threadIdx.x;
    float v = 0.f;
    if (k < KK && d < DD) v = T_w[(size_t)d * KK + k];
    Tt[(size_t)k * TTP + d] = v;
}

// ============ K1: y — wave-per-segment chunk-4 gather ============
__global__ __launch_bounds__(256, 4) void k_y1(
    const float* __restrict__ emb,
    const int*   __restrict__ tokens,
    const int*   __restrict__ seg_starts,
    const int*   __restrict__ seg_lens,
    float* __restrict__ out_y)
{
    const int lane = threadIdx.x & 63;
    const int seg  = blockIdx.x * 4 + (threadIdx.x >> 6);
    const int len  = seg_lens[seg];
    const int base = (seg >> 7) * SS + seg_starts[seg];
    const int tok  = tokens[base + lane];
    const bool bl  = (lane >= 53);

    float4 A[4], B[4];
    #pragma unroll
    for (int i = 0; i < 4; ++i) B[i] = make_float4(0.f, 0.f, 0.f, 0.f);
    float4 aA = make_float4(0.f, 0.f, 0.f, 0.f);
    float4 aB = make_float4(0.f, 0.f, 0.f, 0.f);

    const int len4 = (len + 3) & ~3;
    for (int l0 = 0; l0 < len4; l0 += 4) {
        ld_rows(emb, tok, len, l0, lane, bl, A, B);
        #pragma unroll
        for (int i = 0; i < 4; ++i) {
            const float m = (l0 + i < len) ? 1.f : 0.f;
            fma4(aA, m, A[i]); fma4(aB, m, B[i]);
        }
    }
    const float inv = 1.f / (float)len;
    scale4(aA, inv); scale4(aB, inv);
    float4* yo = (float4*)(out_y + (size_t)seg * DD);
    yo[lane] = aA;
    if (bl) yo[11 + lane] = aB;
}

// ============ K2: u = y @ M_w ============
__global__ __launch_bounds__(NTU) void k_u(
    const float* __restrict__ y,
    const float* __restrict__ M_w,
    float* __restrict__ u)
{
    const int tid  = threadIdx.x;
    const int row0 = blockIdx.x * TMU;
    if (tid >= DD) return;

    float acc[TMU];
    #pragma unroll
    for (int r = 0; r < TMU; ++r) acc[r] = 0.f;

    #pragma unroll 5
    for (int e = 0; e < DD; ++e) {
        const float m = M_w[(size_t)e * DD + tid];
        #pragma unroll
        for (int r = 0; r < TMU; ++r)
            acc[r] += m * y[(size_t)(row0 + r) * DD + e];
    }
    #pragma unroll
    for (int r = 0; r < TMU; ++r)
        u[(size_t)(row0 + r) * DD + tid] = acc[r];
}

// ============ K3: online-softmax fused esc+z, single pass, chunk-4 budgeted ============
__global__ __launch_bounds__(256, 4) void k_rest(
    const float* __restrict__ emb,
    const float* __restrict__ W_w,    // [K, D]
    const float* __restrict__ T_w,    // [D, K] (fallback)
    const float* __restrict__ Tt,     // [TTR, TTP]
    const int    use_tt,
    const int*   __restrict__ tokens,
    const int*   __restrict__ seg_starts,
    const int*   __restrict__ seg_lens,
    const float* __restrict__ u_ws,
    float* __restrict__ out_z,
    float* __restrict__ out_p,
    float* __restrict__ out_r)
{
    const int lane = threadIdx.x & 63;
    const int seg  = blockIdx.x * 4 + (threadIdx.x >> 6);
    const int len  = seg_lens[seg];
    const int base = (seg >> 7) * SS + seg_starts[seg];
    const int tok  = tokens[base + lane];
    const bool bl  = (lane >= 53);

    const float4* u4 = (const float4*)(u_ws + (size_t)seg * DD);
    const float4 U0 = u4[lane];
    float4 U1 = make_float4(0.f, 0.f, 0.f, 0.f);
    if (bl) U1 = u4[11 + lane];

    float4 A[4], B[4];
    #pragma unroll
    for (int i = 0; i < 4; ++i) B[i] = make_float4(0.f, 0.f, 0.f, 0.f);

    // ---- single pass: online softmax-weighted accumulation (branchless rescale) ----
    float m = -INFINITY, s = 0.f;
    float4 zA = make_float4(0.f, 0.f, 0.f, 0.f);
    float4 zB = make_float4(0.f, 0.f, 0.f, 0.f);

    const int len4 = (len + 3) & ~3;
    for (int l0 = 0; l0 < len4; l0 += 4) {
        ld_rows(emb, tok, len, l0, lane, bl, A, B);
        float d0 = wave_sum(dot4(A[0], U0) + dot4(B[0], U1));
        float d1 = wave_sum(dot4(A[1], U0) + dot4(B[1], U1));
        float d2 = wave_sum(dot4(A[2], U0) + dot4(B[2], U1));
        float d3 = wave_sum(dot4(A[3], U0) + dot4(B[3], U1));
        const float e0 = (l0 + 0 < len) ? d0 : -INFINITY;
        const float e1 = (l0 + 1 < len) ? d1 : -INFINITY;
        const float e2 = (l0 + 2 < len) ? d2 : -INFINITY;
        const float e3 = (l0 + 3 < len) ? d3 : -INFINITY;
        const float g  = fmaxf(fmaxf(e0, e1), fmaxf(e2, e3));   // finite (l0 < len)
        const float mn = fmaxf(m, g);
        const float sc = __expf(m - mn);     // first chunk: exp(-inf)=0
        m = mn;
        const float w0 = (l0 + 0 < len) ? __expf(d0 - m) : 0.f;
        const float w1 = (l0 + 1 < len) ? __expf(d1 - m) : 0.f;
        const float w2 = (l0 + 2 < len) ? __expf(d2 - m) : 0.f;
        const float w3 = (l0 + 3 < len) ? __expf(d3 - m) : 0.f;
        s = s * sc + w0 + w1 + w2 + w3;
        scale4(zA, sc); scale4(zB, sc);
        fma4(zA, w0, A[0]); fma4(zB, w0, B[0]);
        fma4(zA, w1, A[1]); fma4(zB, w1, B[1]);
        fma4(zA, w2, A[2]); fma4(zB, w2, B[2]);
        fma4(zA, w3, A[3]); fma4(zB, w3, B[3]);
    }

    const float invs = 1.f / s;
    scale4(zA, invs); scale4(zB, invs);
    {
        float4* zo = (float4*)(out_z + (size_t)seg * DD);
        zo[lane] = zA;
        if (bl) zo[11 + lane] = zB;
    }

    // ---- p: 50 wave-dots vs register z, chunk-4 (rows clamped to 49) ----
    float sc_p = 0.f;
    for (int k0 = 0; k0 < 52; k0 += 4) {
        ld_wrows(W_w, KK - 1, DD, k0, lane, bl, A, B);
        float t0 = wave_sum(dot4(A[0], zA) + dot4(B[0], zB));
        float t1 = wave_sum(dot4(A[1], zA) + dot4(B[1], zB));
        float t2 = wave_sum(dot4(A[2], zA) + dot4(B[2], zB));
        float t3 = wave_sum(dot4(A[3], zA) + dot4(B[3], zB));
        sc_p = (lane == k0 + 0) ? t0 : sc_p;
        sc_p = (lane == k0 + 1) ? t1 : sc_p;
        sc_p = (lane == k0 + 2) ? t2 : sc_p;
        sc_p = (lane == k0 + 3) ? t3 : sc_p;
    }
    const float vk  = (lane < KK) ? sc_p : -INFINITY;
    const float mxk = wave_max(vk);
    const float ek  = (lane < KK) ? __expf(vk - mxk) : 0.f;
    const float smk = wave_sum(ek);
    const float p   = ek / smk;            // 0 for lanes >= 50
    if (lane < KK) out_p[(size_t)seg * KK + lane] = p;

    // ---- r = p @ T_w.T, chunk-4 ----
    float4 rA = make_float4(0.f, 0.f, 0.f, 0.f);
    float4 rB = make_float4(0.f, 0.f, 0.f, 0.f);
    if (use_tt) {
        for (int k0 = 0; k0 < 52; k0 += 4) {   // rows 50+ are zeros; p(k>=50)=0
            ld_wrows(Tt, TTR - 1, TTP, k0, lane, bl, A, B);
            #pragma unroll
            for (int i = 0; i < 4; ++i) {
                const float pk = __shfl(p, k0 + i);
                fma4(rA, pk, A[i]); fma4(rB, pk, B[i]);
            }
        }
    } else {
        const int dA = 4 * lane, dB = 44 + 4 * lane;
        for (int k = 0; k < KK; ++k) {
            const float pk = __shfl(p, k);
            rA.x += pk * T_w[(size_t)(dA + 0) * KK + k];
            rA.y += pk * T_w[(size_t)(dA + 1) * KK + k];
            rA.z += pk * T_w[(size_t)(dA + 2) * KK + k];
            rA.w += pk * T_w[(size_t)(dA + 3) * KK + k];
            if (bl) {
                rB.x += pk * T_w[(size_t)(dB + 0) * KK + k];
                rB.y += pk * T_w[(size_t)(dB + 1) * KK + k];
                rB.z += pk * T_w[(size_t)(dB + 2) * KK + k];
                rB.w += pk * T_w[(size_t)(dB + 3) * KK + k];
            }
        }
    }
    {
        float4* ro = (float4*)(out_r + (size_t)seg * DD);
        ro[lane] = rA;
        if (bl) ro[11 + lane] = rB;
    }
}

extern "C" void kernel_launch(void* const* d_in, const int* in_sizes, int n_in,
                              void* d_out, int out_size, void* d_ws, size_t ws_size,
                              hipStream_t stream) {
    const float* emb        = (const float*)d_in[0];
    const float* M_w        = (const float*)d_in[1];
    const float* W_w        = (const float*)d_in[2];
    const float* T_w        = (const float*)d_in[3];
    const int*   tokens     = (const int*)d_in[4];
    const int*   seg_starts = (const int*)d_in[5];
    const int*   seg_lens   = (const int*)d_in[6];

    float* out   = (float*)d_out;
    float* out_y = out;
    float* out_z = out + (size_t)NSEG * DD;
    float* out_p = out + (size_t)2 * NSEG * DD;
    float* out_r = out + (size_t)2 * NSEG * DD + (size_t)NSEG * KK;

    float* u_ws = (float*)d_ws;                              // NSEG*DD floats
    float* Tt   = u_ws + (size_t)NSEG * DD;                  // TTR*TTP floats
    const size_t need = ((size_t)NSEG * DD + (size_t)TTR * TTP) * sizeof(float);
    const int use_tt = (ws_size >= need) ? 1 : 0;

    if (use_tt)
        hipLaunchKernelGGL(k_tt, dim3(TTR), dim3(TTP), 0, stream, T_w, Tt);
    hipLaunchKernelGGL(k_y1, dim3(NSEG / 4), dim3(256), 0, stream,
                       emb, tokens, seg_starts, seg_lens, out_y);
    hipLaunchKernelGGL(k_u, dim3(NSEG / TMU), dim3(NTU), 0, stream,
                       out_y, M_w, u_ws);
    hipLaunchKernelGGL(k_rest, dim3(NSEG / 4), dim3(256), 0, stream,
                       emb, W_w, T_w, Tt, use_tt, tokens, seg_starts, seg_lens,
                       u_ws, out_z, out_p, out_r);
}